// Round 14
// baseline (1573.468 us; speedup 1.0000x reference)
//
#include <hip/hip_runtime.h>

// GraphSAGE 3-layer forward.
// R14: k_bucket + k_csr fused into k_bucket_csr via per-bucket completion
// counters (k_bhist's last-block-done idiom, validated R11/R13): chunk blocks
// partition edges into bucket regions, threadfence, bump bdone[bucket]; the
// block completing a bucket claims it and runs its per-dst CSR immediately
// (overlaps CSR behind partitioning, deletes one dispatch). Grid covers NB so
// empty buckets are claimed by their index block.
// Rest = R13 (best): k_prep (cast x + pack weights + zero bhist/bdone) ->
// k_bhist (hist + last-block fused bucket scan) -> k_bucket_csr -> 3x k_fused
// (16-node blocks: gather-mean -> swizzled LDS; MFMA 16x128 combine).
// Gather is at the L3/fabric random-256B-fetch floor (~4.7 TB/s effective row
// reads): R7/R9/R12 attacks all null-or-negative. N=50000, E=800000, D=128.
// Requires N <= 65536 (16-bit edge packing).

#define D 128

typedef __attribute__((ext_vector_type(8))) short bf16x8;
typedef __attribute__((ext_vector_type(4))) float f32x4;

__device__ inline ushort f2bf(float f) {
  union { float f; unsigned u; } v; v.f = f;
  unsigned r = v.u + 0x7fffu + ((v.u >> 16) & 1u);
  return (ushort)(r >> 16);
}
__device__ inline float bf2f(ushort h) {
  union { unsigned u; float f; } v; v.u = ((unsigned)h) << 16;
  return v.f;
}

// ---- prep: fp32->bf16 cast of x, pack 3 layers' weights, zero bhist+bdone ----
// blocks [0, castB): cast; [castB, castB+384): pack; last block: zero counters.
// Per layer pack: element idx = ((kk*8+ct)*64 + lane)*8 + j holds
//   B[kk*32+(lane>>4)*8+j][ct*16+(lane&15)]   (B = [Wl;Wr], K=256 x 128)
__global__ void k_prep(const float* __restrict__ x, ushort* __restrict__ xb, int total4,
                       const float* __restrict__ Wl1, const float* __restrict__ Wr1,
                       const float* __restrict__ Wl2, const float* __restrict__ Wr2,
                       const float* __restrict__ Wl3, const float* __restrict__ Wr3,
                       ushort* __restrict__ Bp, int* __restrict__ bhist,
                       int* __restrict__ bdone, int castB) {
  int b = blockIdx.x;
  int t = threadIdx.x;
  if (b < castB) {
    int i = b * 256 + t;
    if (i < total4) {
      float4 v = *reinterpret_cast<const float4*>(x + (size_t)i * 4);
      ushort4 o;
      o.x = f2bf(v.x); o.y = f2bf(v.y); o.z = f2bf(v.z); o.w = f2bf(v.w);
      *reinterpret_cast<ushort4*>(xb + (size_t)i * 4) = o;
    }
  } else if (b < castB + 384) {
    int gidx = (b - castB) * 256 + t;  // 3*32768 total
    int layer = gidx >> 15;
    int idx = gidx & 32767;
    const float* Wl = (layer == 0) ? Wl1 : (layer == 1) ? Wl2 : Wl3;
    const float* Wr = (layer == 0) ? Wr1 : (layer == 1) ? Wr2 : Wr3;
    int kk = idx >> 12;
    int ct = (idx >> 9) & 7;
    int l  = (idx >> 3) & 63;
    int j  = idx & 7;
    int k = kk * 32 + ((l >> 4) << 3) + j;
    int col = ct * 16 + (l & 15);
    float v = (k < 128) ? Wl[k * 128 + col] : Wr[(k - 128) * 128 + col];
    Bp[gidx] = f2bf(v);
  } else {
    for (int i = t; i < 512; i += 256) { bhist[i] = 0; bdone[i] = 0; }
  }
}

// ---- CSR stage 1: bucket histogram + fused scan (last block) ----
// bhist[0..NB): counts; bhist[480]: completion counter.
__global__ __launch_bounds__(256) void k_bhist(const int* __restrict__ dst,
                                               int* __restrict__ bhist,
                                               int* __restrict__ bbase,
                                               int* __restrict__ bcur,
                                               int* __restrict__ offN,
                                               int E, int NB, int nblocks) {
  __shared__ int h[512];
  __shared__ int lastflag;
  int t = threadIdx.x;
  for (int i = t; i < NB; i += 256) h[i] = 0;
  __syncthreads();
  int beg = blockIdx.x * 4096;
  int end = min(beg + 4096, E);
  for (int i = beg + t; i < end; i += 256) atomicAdd(&h[dst[i] >> 7], 1);
  __syncthreads();
  for (int i = t; i < NB; i += 256)
    if (h[i]) atomicAdd(&bhist[i], h[i]);
  __threadfence();
  if (t == 0) lastflag = (atomicAdd(&bhist[480], 1) == nblocks - 1);
  __syncthreads();
  if (!lastflag) return;
  __threadfence();
  // single-wave exclusive scan of NB (<480) bucket counts
  if (t < 64) {
    int lane = t;
    int run = 0;
    for (int base = 0; base < NB; base += 64) {
      int idx = base + lane;
      int orig = (idx < NB) ? bhist[idx] : 0;
      int v = orig;
#pragma unroll
      for (int d = 1; d < 64; d <<= 1) {
        int u = __shfl_up(v, d);
        if (lane >= d) v += u;
      }
      if (idx < NB) {
        int ex = run + v - orig;
        bbase[idx] = ex;
        bcur[idx] = ex;
      }
      run += __shfl(v, 63);
    }
    if (lane == 0) *offN = run;  // == E
  }
}

// ---- CSR stage 2+3 fused: partition into bucket regions, then the block
// that completes a bucket (bdone reaches bhist) claims and CSR-processes it ----
__global__ __launch_bounds__(256) void k_bucket_csr(const int* __restrict__ src,
                                                    const int* __restrict__ dst,
                                                    int* __restrict__ bcur,
                                                    int* __restrict__ bdone,
                                                    const int* __restrict__ bbase,
                                                    const int* __restrict__ bhist,
                                                    unsigned* __restrict__ ebuf,
                                                    int* __restrict__ off,
                                                    float* __restrict__ invd,
                                                    int* __restrict__ srcs,
                                                    int E, int NB, int N) {
  __shared__ int h[512];
  __shared__ int base[512];
  __shared__ int claimed[512];
  __shared__ int nclaimed;
  __shared__ int dcount[128];
  __shared__ int dloc[128];
  int t = threadIdx.x;
  int b = blockIdx.x;
  if (t == 0) nclaimed = 0;
  for (int i = t; i < NB; i += 256) h[i] = 0;
  __syncthreads();

  int beg = b * 4096;
  if (beg < E) {
    // --- partition this chunk (identical to old k_bucket) ---
    int end = min(beg + 4096, E);
    for (int i = beg + t; i < end; i += 256) atomicAdd(&h[dst[i] >> 7], 1);
    __syncthreads();
    for (int i = t; i < NB; i += 256) {
      int c = h[i];
      base[i] = c ? atomicAdd(&bcur[i], c) : 0;
      h[i] = 0;
    }
    __syncthreads();
    for (int i = beg + t; i < end; i += 256) {
      int d = dst[i];
      int bk = d >> 7;
      int r = atomicAdd(&h[bk], 1);
      ebuf[base[bk] + r] = (((unsigned)src[i]) << 16) | (unsigned)d;
    }
    __syncthreads();
    __threadfence();  // make ebuf writes device-visible before completion bump
    // --- completion: claim buckets this block finishes ---
    for (int i = t; i < NB; i += 256) {
      int c = h[i];
      if (c > 0) {
        int w = atomicAdd(&bdone[i], c) + c;
        if (w == bhist[i]) claimed[atomicAdd(&nclaimed, 1)] = i;
      }
    }
  }
  // empty buckets (count 0): claimed by their index block (still need off/invd)
  if (t == 0 && b < NB && bhist[b] == 0) claimed[atomicAdd(&nclaimed, 1)] = b;
  __syncthreads();
  __threadfence();  // acquire: order claims before reading other blocks' ebuf

  // --- CSR-process claimed buckets (old k_csr body per bucket) ---
  int nc = nclaimed;
  for (int k = 0; k < nc; ++k) {
    int bk = claimed[k];
    int bbeg = bbase[bk];
    int bend = bbeg + bhist[bk];
    if (t < 128) dcount[t] = 0;
    __syncthreads();
    for (int i = bbeg + t; i < bend; i += 256) atomicAdd(&dcount[ebuf[i] & 127], 1);
    __syncthreads();
    if (t < 128) dloc[t] = dcount[t];
    __syncthreads();
    for (int d = 1; d < 128; d <<= 1) {
      int x = 0, a = 0;
      if (t < 128) {
        x = dloc[t];
        if (t >= d) a = dloc[t - d];
      }
      __syncthreads();
      if (t < 128) dloc[t] = x + a;
      __syncthreads();
    }
    if (t < 128) {
      int node = bk * 128 + t;
      if (node < N) {
        int ex = bbeg + dloc[t] - dcount[t];
        off[node] = ex;
        int c = dcount[t];
        invd[node] = c > 0 ? 1.0f / (float)c : 0.0f;
        dcount[t] = ex;  // becomes cursor
      }
    }
    __syncthreads();
    for (int i = bbeg + t; i < bend; i += 256) {
      unsigned pk = ebuf[i];
      int slot = atomicAdd(&dcount[pk & 127], 1);
      srcs[slot] = (int)(pk >> 16);
    }
    __syncthreads();
  }
}

// ---- fused layer kernel: 16 nodes per block, 4 waves ----
// Phase 1: wave w gathers nodes node0+w*4..+3 serially; per node:
//   lane=(g,s): g=edge slot (4 edges in flight), s=feature octet (16B),
//   unroll x2 -> 8 outstanding loads; shfl_xor(16,32) reduce; lanes 0-15
//   write the bf16 mean row into LDS at byte nl*256 + (s*16 ^ ((nl&7)<<4)).
// Phase 2: MFMA. Wave w owns cols [w*32, w*32+32) (ct = 2w, 2w+1).
//   A-frag: lane holds A[node0+(l&15)][kk*32+(l>>4)*8+0..7]; kk<4 from LDS
//   (swizzled), kk>=4 from global h row. B pre-packed.
//   C/D: row=(l>>4)*4+reg, col=ct*16+(l&15)  [m89-verified layout]
template <int RELU, int FINAL>
__global__ __launch_bounds__(256, 6) void k_fused(const ushort* __restrict__ hin,
                                                  const int* __restrict__ off,
                                                  const int* __restrict__ srcs,
                                                  const float* __restrict__ invd,
                                                  const ushort* __restrict__ Bpack,
                                                  const float* __restrict__ bias,
                                                  float* __restrict__ outf,
                                                  ushort* __restrict__ outh, int N) {
  __shared__ ushort smean[16 * D];  // 4KB, swizzled
  int t = threadIdx.x;
  int w = t >> 6;
  int lane = t & 63;
  int node0 = blockIdx.x * 16;
  int g = lane >> 4;   // edge slot 0..3
  int s = lane & 15;   // feature octet

  // --- phase 1: gather-mean for this wave's 4 nodes ---
  for (int q = 0; q < 4; ++q) {
    int nl = w * 4 + q;
    int n = node0 + nl;
    float acc[8] = {0.f, 0.f, 0.f, 0.f, 0.f, 0.f, 0.f, 0.f};
    float wgt = 0.f;
    if (n < N) {
      wgt = invd[n];
      int lo = off[n], hi = off[n + 1];
      int e = lo + g;
      for (; e + 4 < hi; e += 8) {
        int i0 = srcs[e];
        int i1 = srcs[e + 4];
        bf16x8 v0 = *reinterpret_cast<const bf16x8*>(hin + (size_t)i0 * D + s * 8);
        bf16x8 v1 = *reinterpret_cast<const bf16x8*>(hin + (size_t)i1 * D + s * 8);
#pragma unroll
        for (int j = 0; j < 8; ++j) acc[j] += bf2f((ushort)v0[j]);
#pragma unroll
        for (int j = 0; j < 8; ++j) acc[j] += bf2f((ushort)v1[j]);
      }
      if (e < hi) {
        int i0 = srcs[e];
        bf16x8 v0 = *reinterpret_cast<const bf16x8*>(hin + (size_t)i0 * D + s * 8);
#pragma unroll
        for (int j = 0; j < 8; ++j) acc[j] += bf2f((ushort)v0[j]);
      }
    }
#pragma unroll
    for (int j = 0; j < 8; ++j) acc[j] += __shfl_xor(acc[j], 16);
#pragma unroll
    for (int j = 0; j < 8; ++j) acc[j] += __shfl_xor(acc[j], 32);
    if (lane < 16) {
      bf16x8 o;
#pragma unroll
      for (int j = 0; j < 8; ++j) o[j] = (short)f2bf(acc[j] * wgt);
      int byte = nl * 256 + ((s * 16) ^ ((nl & 7) << 4));
      *reinterpret_cast<bf16x8*>(reinterpret_cast<char*>(smean) + byte) = o;
    }
  }
  __syncthreads();

  // --- phase 2: MFMA combine, wave w owns ct = 2w, 2w+1 ---
  int lr = lane & 15;
  int kgrp = lane >> 4;
  int arow = node0 + lr;
  if (arow >= N) arow = N - 1;  // clamp loads; stores guarded
  size_t abase = (size_t)arow * D;

  f32x4 acc2[2];
#pragma unroll
  for (int i = 0; i < 2; ++i) {
    float bv = bias[(w * 2 + i) * 16 + lr];
    acc2[i] = (f32x4){bv, bv, bv, bv};
  }

#pragma unroll
  for (int kk = 0; kk < 8; ++kk) {
    int klocal = ((kk & 3) << 5) + (kgrp << 3);
    bf16x8 a;
    if (kk < 4) {
      int byte = lr * 256 + ((klocal * 2) ^ ((lr & 7) << 4));
      a = *reinterpret_cast<const bf16x8*>(reinterpret_cast<const char*>(smean) + byte);
    } else {
      a = *reinterpret_cast<const bf16x8*>(hin + abase + klocal);
    }
#pragma unroll
    for (int i = 0; i < 2; ++i) {
      int ct = w * 2 + i;
      bf16x8 b = *reinterpret_cast<const bf16x8*>(Bpack + (((size_t)(kk * 8 + ct) * 64 + lane) << 3));
      acc2[i] = __builtin_amdgcn_mfma_f32_16x16x32_bf16(a, b, acc2[i], 0, 0, 0);
    }
  }

#pragma unroll
  for (int i = 0; i < 2; ++i) {
    int c = (w * 2 + i) * 16 + lr;
#pragma unroll
    for (int r = 0; r < 4; ++r) {
      int rr = node0 + kgrp * 4 + r;
      if (rr < N) {
        float v = acc2[i][r];
        if (RELU) v = fmaxf(v, 0.f);
        if (FINAL) outf[(size_t)rr * D + c] = v;
        else outh[(size_t)rr * D + c] = f2bf(v);
      }
    }
  }
}

extern "C" void kernel_launch(void* const* d_in, const int* in_sizes, int n_in,
                              void* d_out, int out_size, void* d_ws, size_t ws_size,
                              hipStream_t stream) {
  const float* x   = (const float*)d_in[0];
  const int*   ei  = (const int*)d_in[1];
  const float* Wl1 = (const float*)d_in[2];
  const float* b1  = (const float*)d_in[3];
  const float* Wr1 = (const float*)d_in[4];
  const float* Wl2 = (const float*)d_in[5];
  const float* b2  = (const float*)d_in[6];
  const float* Wr2 = (const float*)d_in[7];
  const float* Wl3 = (const float*)d_in[8];
  const float* b3  = (const float*)d_in[9];
  const float* Wr3 = (const float*)d_in[10];
  float* out = (float*)d_out;

  int N = in_sizes[0] / D;
  int E = in_sizes[1] / 2;
  const int* srcp = ei;
  const int* dstp = ei + E;
  int NB = (N + 127) >> 7;  // 391 for N=50000

  char* p = (char*)d_ws;
  auto carve = [&](size_t bytes) {
    void* r = (void*)p;
    p += (bytes + 255) & ~(size_t)255;
    return r;
  };
  int*      bhist = (int*)carve((size_t)512 * 4);  // [480] = completion counter
  int*      bdone = (int*)carve((size_t)512 * 4);
  int*      bbase = (int*)carve((size_t)512 * 4);
  int*      bcur  = (int*)carve((size_t)512 * 4);
  int*      off   = (int*)carve((size_t)(N + 1) * 4);
  float*    invd  = (float*)carve((size_t)N * 4);
  int*      srcs  = (int*)carve((size_t)E * 4);
  unsigned* ebuf  = (unsigned*)carve((size_t)E * 4);
  ushort*   xb    = (ushort*)carve((size_t)N * D * 2);
  ushort*   h1b   = (ushort*)carve((size_t)N * D * 2);
  ushort*   h2b   = (ushort*)carve((size_t)N * D * 2);
  ushort*   Bp    = (ushort*)carve((size_t)3 * 32768 * 2);

  // --- prep (cast + pack + zero bhist/bdone), one dispatch ---
  int total4 = N * D / 4;
  int castB = (total4 + 255) / 256;
  k_prep<<<castB + 384 + 1, 256, 0, stream>>>(x, xb, total4, Wl1, Wr1, Wl2, Wr2,
                                              Wl3, Wr3, Bp, bhist, bdone, castB);

  // --- CSR build (bucketed, 2 dispatches) ---
  int ch_blocks = (E + 4095) / 4096;
  k_bhist<<<ch_blocks, 256, 0, stream>>>(dstp, bhist, bbase, bcur, off + N, E, NB, ch_blocks);
  int bc_blocks = ch_blocks > NB ? ch_blocks : NB;
  k_bucket_csr<<<bc_blocks, 256, 0, stream>>>(srcp, dstp, bcur, bdone, bbase, bhist,
                                              ebuf, off, invd, srcs, E, NB, N);

  int fused_blocks = (N + 15) / 16;  // 3125

  // --- fused layers ---
  k_fused<1, 0><<<fused_blocks, 256, 0, stream>>>(xb, off, srcs, invd, Bp, b1, nullptr, h1b, N);
  k_fused<1, 0><<<fused_blocks, 256, 0, stream>>>(h1b, off, srcs, invd, Bp + 32768, b2, nullptr, h2b, N);
  k_fused<0, 1><<<fused_blocks, 256, 0, stream>>>(h2b, off, srcs, invd, Bp + 2 * 32768, b3, out, nullptr, N);
}

// Round 15
// 181.178 us; speedup vs baseline: 8.6847x; 8.6847x over previous
//
#include <hip/hip_runtime.h>

// GraphSAGE 3-layer forward.  (R15 = exact revert to R13/R11, the best config.)
// R14's bucket+CSR fusion regressed 8.6x: per-bucket completion-claims are
// won by the LAST contributing block, and with ~196 dense chunks every bucket
// was claimed by the tail block(s) -> ~391 buckets CSR-processed serially in
// one block (occupancy 0.35%, 2ms). Claim-based work distribution is skewed;
// keeping the 2-dispatch CSR.
// Ledger: gather is at the L3/fabric random-256B-fetch floor (~4.7 TB/s
// effective row reads; R7 wider loads / R9 deeper MLP / R12 windowing all
// null-or-negative). Fusion of gather+combine pays only with full TLP
// (R8 16-node blocks vs R5 64-node). Dispatch-count fusion is noise (R10/R11).
// Pipeline: k_prep (cast x + pack weights + zero bhist) -> k_bhist (hist +
// last-block fused bucket scan) -> k_bucket (packed (src<<16|dst) into bucket
// regions) -> k_csr (per-dst -> off/invd/srcs) -> 3x k_fused (16-node blocks:
// gather-mean -> swizzled LDS; MFMA 16x128 combine, B pre-packed).
// N=50000, E=800000, D=128, K=256. Requires N <= 65536 (16-bit edge packing).

#define D 128

typedef __attribute__((ext_vector_type(8))) short bf16x8;
typedef __attribute__((ext_vector_type(4))) float f32x4;

__device__ inline ushort f2bf(float f) {
  union { float f; unsigned u; } v; v.f = f;
  unsigned r = v.u + 0x7fffu + ((v.u >> 16) & 1u);
  return (ushort)(r >> 16);
}
__device__ inline float bf2f(ushort h) {
  union { unsigned u; float f; } v; v.u = ((unsigned)h) << 16;
  return v.f;
}

// ---- prep: fp32->bf16 cast of x, pack 3 layers' weights, zero bhist ----
// blocks [0, castB): cast; [castB, castB+384): pack; last block: zero bhist.
// Per layer pack: element idx = ((kk*8+ct)*64 + lane)*8 + j holds
//   B[kk*32+(lane>>4)*8+j][ct*16+(lane&15)]   (B = [Wl;Wr], K=256 x 128)
__global__ void k_prep(const float* __restrict__ x, ushort* __restrict__ xb, int total4,
                       const float* __restrict__ Wl1, const float* __restrict__ Wr1,
                       const float* __restrict__ Wl2, const float* __restrict__ Wr2,
                       const float* __restrict__ Wl3, const float* __restrict__ Wr3,
                       ushort* __restrict__ Bp, int* __restrict__ bhist, int castB) {
  int b = blockIdx.x;
  int t = threadIdx.x;
  if (b < castB) {
    int i = b * 256 + t;
    if (i < total4) {
      float4 v = *reinterpret_cast<const float4*>(x + (size_t)i * 4);
      ushort4 o;
      o.x = f2bf(v.x); o.y = f2bf(v.y); o.z = f2bf(v.z); o.w = f2bf(v.w);
      *reinterpret_cast<ushort4*>(xb + (size_t)i * 4) = o;
    }
  } else if (b < castB + 384) {
    int gidx = (b - castB) * 256 + t;  // 3*32768 total
    int layer = gidx >> 15;
    int idx = gidx & 32767;
    const float* Wl = (layer == 0) ? Wl1 : (layer == 1) ? Wl2 : Wl3;
    const float* Wr = (layer == 0) ? Wr1 : (layer == 1) ? Wr2 : Wr3;
    int kk = idx >> 12;
    int ct = (idx >> 9) & 7;
    int l  = (idx >> 3) & 63;
    int j  = idx & 7;
    int k = kk * 32 + ((l >> 4) << 3) + j;
    int col = ct * 16 + (l & 15);
    float v = (k < 128) ? Wl[k * 128 + col] : Wr[(k - 128) * 128 + col];
    Bp[gidx] = f2bf(v);
  } else {
    for (int i = t; i < 512; i += 256) bhist[i] = 0;
  }
}

// ---- CSR stage 1: bucket histogram + fused scan (last block) ----
// bhist[0..NB): counts; bhist[480]: completion counter.
__global__ __launch_bounds__(256) void k_bhist(const int* __restrict__ dst,
                                               int* __restrict__ bhist,
                                               int* __restrict__ bbase,
                                               int* __restrict__ bcur,
                                               int* __restrict__ offN,
                                               int E, int NB, int nblocks) {
  __shared__ int h[512];
  __shared__ int lastflag;
  int t = threadIdx.x;
  for (int i = t; i < NB; i += 256) h[i] = 0;
  __syncthreads();
  int beg = blockIdx.x * 4096;
  int end = min(beg + 4096, E);
  for (int i = beg + t; i < end; i += 256) atomicAdd(&h[dst[i] >> 7], 1);
  __syncthreads();
  for (int i = t; i < NB; i += 256)
    if (h[i]) atomicAdd(&bhist[i], h[i]);
  __threadfence();
  if (t == 0) lastflag = (atomicAdd(&bhist[480], 1) == nblocks - 1);
  __syncthreads();
  if (!lastflag) return;
  __threadfence();
  // single-wave exclusive scan of NB (<480) bucket counts
  if (t < 64) {
    int lane = t;
    int run = 0;
    for (int base = 0; base < NB; base += 64) {
      int idx = base + lane;
      int orig = (idx < NB) ? bhist[idx] : 0;
      int v = orig;
#pragma unroll
      for (int d = 1; d < 64; d <<= 1) {
        int u = __shfl_up(v, d);
        if (lane >= d) v += u;
      }
      if (idx < NB) {
        int ex = run + v - orig;
        bbase[idx] = ex;
        bcur[idx] = ex;
      }
      run += __shfl(v, 63);
    }
    if (lane == 0) *offN = run;  // == E
  }
}

// ---- CSR stage 2: partition edges into bucket regions (packed u32) ----
__global__ __launch_bounds__(256) void k_bucket(const int* __restrict__ src,
                                                const int* __restrict__ dst,
                                                int* __restrict__ bcur,
                                                unsigned* __restrict__ ebuf,
                                                int E, int NB) {
  __shared__ int h[512];
  __shared__ int base[512];
  int t = threadIdx.x;
  for (int i = t; i < NB; i += 256) h[i] = 0;
  __syncthreads();
  int beg = blockIdx.x * 4096;
  int end = min(beg + 4096, E);
  for (int i = beg + t; i < end; i += 256) atomicAdd(&h[dst[i] >> 7], 1);
  __syncthreads();
  for (int i = t; i < NB; i += 256) {
    int c = h[i];
    base[i] = c ? atomicAdd(&bcur[i], c) : 0;
    h[i] = 0;
  }
  __syncthreads();
  for (int i = beg + t; i < end; i += 256) {
    int d = dst[i];
    int b = d >> 7;
    int r = atomicAdd(&h[b], 1);
    ebuf[base[b] + r] = (((unsigned)src[i]) << 16) | (unsigned)d;
  }
}

// ---- CSR stage 3: per-bucket per-dst CSR (one block per bucket) ----
__global__ __launch_bounds__(256) void k_csr(const unsigned* __restrict__ ebuf,
                                             const int* __restrict__ bbase,
                                             const int* __restrict__ bhist,
                                             int* __restrict__ off,
                                             float* __restrict__ invd,
                                             int* __restrict__ srcs, int N) {
  __shared__ int dcount[128];
  __shared__ int dloc[128];
  int b = blockIdx.x;
  int t = threadIdx.x;
  int beg = bbase[b];
  int end = beg + bhist[b];
  if (t < 128) dcount[t] = 0;
  __syncthreads();
  for (int i = beg + t; i < end; i += 256) atomicAdd(&dcount[ebuf[i] & 127], 1);
  __syncthreads();
  if (t < 128) dloc[t] = dcount[t];
  __syncthreads();
  for (int d = 1; d < 128; d <<= 1) {
    int x = 0, a = 0;
    if (t < 128) {
      x = dloc[t];
      if (t >= d) a = dloc[t - d];
    }
    __syncthreads();
    if (t < 128) dloc[t] = x + a;
    __syncthreads();
  }
  if (t < 128) {
    int node = b * 128 + t;
    if (node < N) {
      int ex = beg + dloc[t] - dcount[t];
      off[node] = ex;
      int c = dcount[t];
      invd[node] = c > 0 ? 1.0f / (float)c : 0.0f;
      dcount[t] = ex;  // becomes cursor
    }
  }
  __syncthreads();
  for (int i = beg + t; i < end; i += 256) {
    unsigned p = ebuf[i];
    int slot = atomicAdd(&dcount[p & 127], 1);
    srcs[slot] = (int)(p >> 16);
  }
}

// ---- fused layer kernel: 16 nodes per block, 4 waves ----
// Phase 1: wave w gathers nodes node0+w*4..+3 serially; per node:
//   lane=(g,s): g=edge slot (4 edges in flight), s=feature octet (16B),
//   unroll x2 -> 8 outstanding loads; shfl_xor(16,32) reduce; lanes 0-15
//   write the bf16 mean row into LDS at byte nl*256 + (s*16 ^ ((nl&7)<<4)).
// Phase 2: MFMA. Wave w owns cols [w*32, w*32+32) (ct = 2w, 2w+1).
//   A-frag: lane holds A[node0+(l&15)][kk*32+(l>>4)*8+0..7]; kk<4 from LDS
//   (swizzled), kk>=4 from global h row. B pre-packed.
//   C/D: row=(l>>4)*4+reg, col=ct*16+(l&15)  [m89-verified layout]
template <int RELU, int FINAL>
__global__ __launch_bounds__(256, 6) void k_fused(const ushort* __restrict__ hin,
                                                  const int* __restrict__ off,
                                                  const int* __restrict__ srcs,
                                                  const float* __restrict__ invd,
                                                  const ushort* __restrict__ Bpack,
                                                  const float* __restrict__ bias,
                                                  float* __restrict__ outf,
                                                  ushort* __restrict__ outh, int N) {
  __shared__ ushort smean[16 * D];  // 4KB, swizzled
  int t = threadIdx.x;
  int w = t >> 6;
  int lane = t & 63;
  int node0 = blockIdx.x * 16;
  int g = lane >> 4;   // edge slot 0..3
  int s = lane & 15;   // feature octet

  // --- phase 1: gather-mean for this wave's 4 nodes ---
  for (int q = 0; q < 4; ++q) {
    int nl = w * 4 + q;
    int n = node0 + nl;
    float acc[8] = {0.f, 0.f, 0.f, 0.f, 0.f, 0.f, 0.f, 0.f};
    float wgt = 0.f;
    if (n < N) {
      wgt = invd[n];
      int lo = off[n], hi = off[n + 1];
      int e = lo + g;
      for (; e + 4 < hi; e += 8) {
        int i0 = srcs[e];
        int i1 = srcs[e + 4];
        bf16x8 v0 = *reinterpret_cast<const bf16x8*>(hin + (size_t)i0 * D + s * 8);
        bf16x8 v1 = *reinterpret_cast<const bf16x8*>(hin + (size_t)i1 * D + s * 8);
#pragma unroll
        for (int j = 0; j < 8; ++j) acc[j] += bf2f((ushort)v0[j]);
#pragma unroll
        for (int j = 0; j < 8; ++j) acc[j] += bf2f((ushort)v1[j]);
      }
      if (e < hi) {
        int i0 = srcs[e];
        bf16x8 v0 = *reinterpret_cast<const bf16x8*>(hin + (size_t)i0 * D + s * 8);
#pragma unroll
        for (int j = 0; j < 8; ++j) acc[j] += bf2f((ushort)v0[j]);
      }
    }
#pragma unroll
    for (int j = 0; j < 8; ++j) acc[j] += __shfl_xor(acc[j], 16);
#pragma unroll
    for (int j = 0; j < 8; ++j) acc[j] += __shfl_xor(acc[j], 32);
    if (lane < 16) {
      bf16x8 o;
#pragma unroll
      for (int j = 0; j < 8; ++j) o[j] = (short)f2bf(acc[j] * wgt);
      int byte = nl * 256 + ((s * 16) ^ ((nl & 7) << 4));
      *reinterpret_cast<bf16x8*>(reinterpret_cast<char*>(smean) + byte) = o;
    }
  }
  __syncthreads();

  // --- phase 2: MFMA combine, wave w owns ct = 2w, 2w+1 ---
  int lr = lane & 15;
  int kgrp = lane >> 4;
  int arow = node0 + lr;
  if (arow >= N) arow = N - 1;  // clamp loads; stores guarded
  size_t abase = (size_t)arow * D;

  f32x4 acc2[2];
#pragma unroll
  for (int i = 0; i < 2; ++i) {
    float bv = bias[(w * 2 + i) * 16 + lr];
    acc2[i] = (f32x4){bv, bv, bv, bv};
  }

#pragma unroll
  for (int kk = 0; kk < 8; ++kk) {
    int klocal = ((kk & 3) << 5) + (kgrp << 3);
    bf16x8 a;
    if (kk < 4) {
      int byte = lr * 256 + ((klocal * 2) ^ ((lr & 7) << 4));
      a = *reinterpret_cast<const bf16x8*>(reinterpret_cast<const char*>(smean) + byte);
    } else {
      a = *reinterpret_cast<const bf16x8*>(hin + abase + klocal);
    }
#pragma unroll
    for (int i = 0; i < 2; ++i) {
      int ct = w * 2 + i;
      bf16x8 b = *reinterpret_cast<const bf16x8*>(Bpack + (((size_t)(kk * 8 + ct) * 64 + lane) << 3));
      acc2[i] = __builtin_amdgcn_mfma_f32_16x16x32_bf16(a, b, acc2[i], 0, 0, 0);
    }
  }

#pragma unroll
  for (int i = 0; i < 2; ++i) {
    int c = (w * 2 + i) * 16 + lr;
#pragma unroll
    for (int r = 0; r < 4; ++r) {
      int rr = node0 + kgrp * 4 + r;
      if (rr < N) {
        float v = acc2[i][r];
        if (RELU) v = fmaxf(v, 0.f);
        if (FINAL) outf[(size_t)rr * D + c] = v;
        else outh[(size_t)rr * D + c] = f2bf(v);
      }
    }
  }
}

extern "C" void kernel_launch(void* const* d_in, const int* in_sizes, int n_in,
                              void* d_out, int out_size, void* d_ws, size_t ws_size,
                              hipStream_t stream) {
  const float* x   = (const float*)d_in[0];
  const int*   ei  = (const int*)d_in[1];
  const float* Wl1 = (const float*)d_in[2];
  const float* b1  = (const float*)d_in[3];
  const float* Wr1 = (const float*)d_in[4];
  const float* Wl2 = (const float*)d_in[5];
  const float* b2  = (const float*)d_in[6];
  const float* Wr2 = (const float*)d_in[7];
  const float* Wl3 = (const float*)d_in[8];
  const float* b3  = (const float*)d_in[9];
  const float* Wr3 = (const float*)d_in[10];
  float* out = (float*)d_out;

  int N = in_sizes[0] / D;
  int E = in_sizes[1] / 2;
  const int* srcp = ei;
  const int* dstp = ei + E;
  int NB = (N + 127) >> 7;  // 391 for N=50000

  char* p = (char*)d_ws;
  auto carve = [&](size_t bytes) {
    void* r = (void*)p;
    p += (bytes + 255) & ~(size_t)255;
    return r;
  };
  int*      bhist = (int*)carve((size_t)512 * 4);  // [480] = completion counter
  int*      bbase = (int*)carve((size_t)512 * 4);
  int*      bcur  = (int*)carve((size_t)512 * 4);
  int*      off   = (int*)carve((size_t)(N + 1) * 4);
  float*    invd  = (float*)carve((size_t)N * 4);
  int*      srcs  = (int*)carve((size_t)E * 4);
  unsigned* ebuf  = (unsigned*)carve((size_t)E * 4);
  ushort*   xb    = (ushort*)carve((size_t)N * D * 2);
  ushort*   h1b   = (ushort*)carve((size_t)N * D * 2);
  ushort*   h2b   = (ushort*)carve((size_t)N * D * 2);
  ushort*   Bp    = (ushort*)carve((size_t)3 * 32768 * 2);

  // --- prep (cast + pack + bhist zero), one dispatch ---
  int total4 = N * D / 4;
  int castB = (total4 + 255) / 256;
  k_prep<<<castB + 384 + 1, 256, 0, stream>>>(x, xb, total4, Wl1, Wr1, Wl2, Wr2,
                                              Wl3, Wr3, Bp, bhist, castB);

  // --- CSR build (bucketed) ---
  int ch_blocks = (E + 4095) / 4096;
  k_bhist<<<ch_blocks, 256, 0, stream>>>(dstp, bhist, bbase, bcur, off + N, E, NB, ch_blocks);
  k_bucket<<<ch_blocks, 256, 0, stream>>>(srcp, dstp, bcur, ebuf, E, NB);
  k_csr<<<NB, 256, 0, stream>>>(ebuf, bbase, bhist, off, invd, srcs, N);

  int fused_blocks = (N + 15) / 16;  // 3125

  // --- fused layers ---
  k_fused<1, 0><<<fused_blocks, 256, 0, stream>>>(xb, off, srcs, invd, Bp, b1, nullptr, h1b, N);
  k_fused<1, 0><<<fused_blocks, 256, 0, stream>>>(h1b, off, srcs, invd, Bp + 32768, b2, nullptr, h2b, N);
  k_fused<0, 1><<<fused_blocks, 256, 0, stream>>>(h2b, off, srcs, invd, Bp + 2 * 32768, b3, out, nullptr, N);
}